// Round 10
// baseline (179.987 us; speedup 1.0000x reference)
//
#include <hip/hip_runtime.h>

// x [32,64,64,64] f32, emb [64,1024] f32 -> out [ q: 8388608 f32 ][ idx: 131072 f32 ]
// Round 10: minimal diff vs the r9-passing kernel (101 us). Issue MFMA chain
// sets for t AND t+1 back-to-back (8 independent chains in flight), THEN run
// both epilogues: epilogue(t) starts ~155+ cyc after set-P's chains issued,
// so the accvgpr reads no longer eat the full chain latency. Next pair's B
// loads issued between MFMA and epilogues (covered by ~320 cyc of VALU).
// Per-(pixel,k) arithmetic bit-identical to r3/r4/r9 (absmax 0.0).

using half8 = __attribute__((ext_vector_type(8))) _Float16;
using half4 = __attribute__((ext_vector_type(4))) _Float16;
using f32x4 = __attribute__((ext_vector_type(4))) float;

#define XPITCH 72   // halfs per x-row in LDS: 64 + 8 pad

__global__ void prep_kernel(const float* __restrict__ emb,
                            float* __restrict__ e2,
                            _Float16* __restrict__ eTh,
                            _Float16* __restrict__ eTl) {
    const int tx = threadIdx.x;
    const int k  = blockIdx.x * 64 + (tx & 63);   // 16 blocks x 64 ks
    const int cg = tx >> 6;                        // 0..3
#pragma unroll
    for (int cc = 0; cc < 2; ++cc) {
        const int c = cg + cc * 4;                 // 8-d group
        half8 hv, lv;
#pragma unroll
        for (int j = 0; j < 8; ++j) {
            float v = emb[(c * 8 + j) * 1024 + k]; // coalesced over k
            _Float16 h = (_Float16)v;
            hv[j] = h;
            lv[j] = (_Float16)(v - (float)h);      // exact residual
        }
        *(half8*)(eTh + k * 64 + c * 8) = hv;
        *(half8*)(eTl + k * 64 + c * 8) = lv;
    }
    if (cg == 0) {                                 // e2: serial ascending-d fmaf
        float s = 0.f;
#pragma unroll
        for (int d = 0; d < 64; ++d) {
            float v = emb[d * 1024 + k];
            s = fmaf(v, v, s);
        }
        e2[k] = s;
    }
}

__launch_bounds__(256)
__global__ void vq_kernel(const float* __restrict__ x,
                          const _Float16* __restrict__ eTh,
                          const _Float16* __restrict__ eTl,
                          const float* __restrict__ e2,
                          const float* __restrict__ emb,
                          float* __restrict__ outq,
                          float* __restrict__ outidx) {
    __shared__ _Float16 sxh[64 * XPITCH];
    __shared__ _Float16 sxl[64 * XPITCH];
    __shared__ float rbest[256];
    __shared__ int   ridx[256];
    __shared__ int   samin[64];

    const int tx = threadIdx.x;
    const int n0 = blockIdx.x * 64;
    const int bb = n0 >> 12;
    const int hw = n0 & 4095;
    const float* xbase = x + bb * 262144 + hw;

    // ---- stage x -> LDS [p][d] as f16 hi/lo --------------------------------
    {
        const int p  = tx & 63;
        const int dg = (tx >> 6) << 2;
#pragma unroll
        for (int it = 0; it < 4; ++it) {
            int d0 = it * 16 + dg;
            float v0 = xbase[(d0 + 0) * 4096 + p];
            float v1 = xbase[(d0 + 1) * 4096 + p];
            float v2 = xbase[(d0 + 2) * 4096 + p];
            float v3 = xbase[(d0 + 3) * 4096 + p];
            _Float16 h0 = (_Float16)v0, h1 = (_Float16)v1,
                     h2 = (_Float16)v2, h3 = (_Float16)v3;
            half4 hv = {h0, h1, h2, h3};
            half4 lv = {(_Float16)(v0 - (float)h0), (_Float16)(v1 - (float)h1),
                        (_Float16)(v2 - (float)h2), (_Float16)(v3 - (float)h3)};
            *(half4*)(sxh + p * XPITCH + d0) = hv;
            *(half4*)(sxl + p * XPITCH + d0) = lv;
        }
    }
    __syncthreads();

    const int lane = tx & 63;
    const int w    = tx >> 6;
    const int r16  = lane & 15;
    const int q    = lane >> 4;

    // ---- A-fragments, loaded once, pinned ----------------------------------
    half8 ah[4][2], al[4][2];
#pragma unroll
    for (int mt = 0; mt < 4; ++mt)
#pragma unroll
        for (int s = 0; s < 2; ++s) {
            ah[mt][s] = *(const half8*)(sxh + (mt * 16 + r16) * XPITCH + s * 32 + q * 8);
            al[mt][s] = *(const half8*)(sxl + (mt * 16 + r16) * XPITCH + s * 32 + q * 8);
        }
#pragma unroll
    for (int mt = 0; mt < 4; ++mt)
#pragma unroll
        for (int s = 0; s < 2; ++s) {
            asm volatile("" : "+v"(ah[mt][s]));   // forbid LDS remat in loop
            asm volatile("" : "+v"(al[mt][s]));
        }

    float best[16];
    int   bestk[16];
#pragma unroll
    for (int i = 0; i < 16; ++i) { best[i] = 3.4e38f; bestk[i] = 0; }

    const int kw = w << 8;
    const _Float16* bhbase = eTh + (kw + r16) * 64 + q * 8;
    const _Float16* blbase = eTl + (kw + r16) * 64 + q * 8;
    const float*    e2base = e2 + kw + r16;

    half8 pbh0, pbh1, pbl0, pbl1; float pe2;
    half8 qbh0, qbh1, qbl0, qbl1; float qe2;
    f32x4 accP[4], accQ[4];
    float e2P, e2Q;

#define LOADSET(BH0, BH1, BL0, BL1, E2V, TT)                                  \
    {                                                                         \
        const int off_ = (TT) << 10;  /* 16 k-rows * 64 halfs */              \
        BH0 = *(const half8*)(bhbase + off_);                                 \
        BH1 = *(const half8*)(bhbase + off_ + 32);                            \
        BL0 = *(const half8*)(blbase + off_);                                 \
        BL1 = *(const half8*)(blbase + off_ + 32);                            \
        E2V = e2base[(TT) << 4];                                              \
    }

#define MFMA4(BH0, BH1, BL0, BL1, ACC)                                        \
    {                                                                         \
        _Pragma("unroll")                                                     \
        for (int mt = 0; mt < 4; ++mt) {                                      \
            f32x4 a = {0.f, 0.f, 0.f, 0.f};                                   \
            a = __builtin_amdgcn_mfma_f32_16x16x32_f16(al[mt][0], BL0, a, 0, 0, 0); \
            a = __builtin_amdgcn_mfma_f32_16x16x32_f16(al[mt][1], BL1, a, 0, 0, 0); \
            a = __builtin_amdgcn_mfma_f32_16x16x32_f16(al[mt][0], BH0, a, 0, 0, 0); \
            a = __builtin_amdgcn_mfma_f32_16x16x32_f16(al[mt][1], BH1, a, 0, 0, 0); \
            a = __builtin_amdgcn_mfma_f32_16x16x32_f16(ah[mt][0], BL0, a, 0, 0, 0); \
            a = __builtin_amdgcn_mfma_f32_16x16x32_f16(ah[mt][1], BL1, a, 0, 0, 0); \
            a = __builtin_amdgcn_mfma_f32_16x16x32_f16(ah[mt][0], BH0, a, 0, 0, 0); \
            a = __builtin_amdgcn_mfma_f32_16x16x32_f16(ah[mt][1], BH1, a, 0, 0, 0); \
            ACC[mt] = a;                                                      \
        }                                                                     \
    }

#define EPILOGUE(ACC, E2V, TT)                                                \
    {                                                                         \
        const int klc_ = kw + ((TT) << 4) + r16;                              \
        _Pragma("unroll")                                                     \
        for (int mt = 0; mt < 4; ++mt)                                        \
            _Pragma("unroll")                                                 \
            for (int rr = 0; rr < 4; ++rr) {                                  \
                float dist_ = fmaf(-2.f, ACC[mt][rr], E2V);                   \
                int i_ = mt * 4 + rr;                                         \
                if (dist_ < best[i_]) { best[i_] = dist_; bestk[i_] = klc_; } \
            }                                                                 \
    }

    LOADSET(pbh0, pbh1, pbl0, pbl1, pe2, 0);
    LOADSET(qbh0, qbh1, qbl0, qbl1, qe2, 1);
#pragma unroll 1
    for (int t = 0; t < 16; t += 2) {
        // issue both chain sets first (8 independent chains in flight)
        MFMA4(pbh0, pbh1, pbl0, pbl1, accP); e2P = pe2;
        MFMA4(qbh0, qbh1, qbl0, qbl1, accQ); e2Q = qe2;
        // prefetch next pair (WAR on B-regs after MFMA issue is safe; the
        // vmcnt wait lands behind ~320 cyc of epilogue VALU)
        LOADSET(pbh0, pbh1, pbl0, pbl1, pe2, (t + 2) & 15);  // wrap unused at t=14
        LOADSET(qbh0, qbh1, qbl0, qbl1, qe2, (t + 3) & 15);
        // epilogues: accP has had a full MFMA4-issue of slack, accQ has
        // epilogue-P's VALU on top
        EPILOGUE(accP, e2P, t);
        EPILOGUE(accQ, e2Q, t + 1);
    }

    // ---- per-pixel argmin across the 16 lanes sharing a C-row --------------
#pragma unroll
    for (int i = 0; i < 16; ++i) {
        float bv = best[i];
        int   bk = bestk[i];
#pragma unroll
        for (int m = 1; m < 16; m <<= 1) {
            float ov = __shfl_xor(bv, m, 64);
            int   ok = __shfl_xor(bk, m, 64);
            if (ov < bv || (ov == bv && ok < bk)) { bv = ov; bk = ok; }
        }
        best[i] = bv;
        bestk[i] = bk;
    }
    if (r16 == 0) {
#pragma unroll
        for (int mt = 0; mt < 4; ++mt)
#pragma unroll
            for (int rr = 0; rr < 4; ++rr) {
                int p = mt * 16 + q * 4 + rr;
                rbest[w * 64 + p] = best[mt * 4 + rr];
                ridx[w * 64 + p]  = bestk[mt * 4 + rr];
            }
    }
    __syncthreads();

    // ---- cross-wave merge (ascending wave = ascending k) -------------------
    if (tx < 64) {
        float bv = rbest[tx];
        int   bk = ridx[tx];
#pragma unroll
        for (int g = 1; g < 4; ++g) {
            float v  = rbest[g * 64 + tx];
            int   kk = ridx[g * 64 + tx];
            if (v < bv || (v == bv && kk < bk)) { bv = v; bk = kk; }
        }
        samin[tx] = bk;
        outidx[n0 + tx] = (float)bk;
    }
    __syncthreads();

    // ---- gather exact fp32 codebook rows -> output -------------------------
    const int p = tx & 63;
    const int drow = tx >> 6;
    const int amin = samin[p];
    float* obase = outq + bb * 262144 + hw + p;
#pragma unroll
    for (int it = 0; it < 16; ++it) {
        int d = (it << 2) + drow;
        obase[d * 4096] = emb[d * 1024 + amin];
    }
}

extern "C" void kernel_launch(void* const* d_in, const int* in_sizes, int n_in,
                              void* d_out, int out_size, void* d_ws, size_t ws_size,
                              hipStream_t stream) {
    const float* x   = (const float*)d_in[0];
    const float* emb = (const float*)d_in[1];
    float* outq   = (float*)d_out;
    float* outidx = outq + 8388608;

    float*    e2  = (float*)d_ws;                               // 4 KB
    _Float16* eTh = (_Float16*)((char*)d_ws + 4096);            // 128 KB
    _Float16* eTl = (_Float16*)((char*)d_ws + 4096 + 131072);   // 128 KB

    prep_kernel<<<16, 256, 0, stream>>>(emb, e2, eTh, eTl);
    vq_kernel<<<2048, 256, 0, stream>>>(x, eTh, eTl, e2, emb, outq, outidx);
}